// Round 6
// baseline (1728.640 us; speedup 1.0000x reference)
//
#include <hip/hip_runtime.h>
#include <math.h>

// Problem constants (fixed by the reference).
#define N_NODES 50000
#define N_EDGES 640000   // divisible by 32 (20000 tiles) and 256
#define NLAYER  4
#define NPAD    50016    // N_NODES rounded up to 32

typedef unsigned short bf16_t;
typedef __attribute__((ext_vector_type(8))) short s16x8;   // 8 bf16 = 4 VGPR (MFMA A/B frag)
typedef __attribute__((ext_vector_type(4))) float f32x4;   // MFMA C/D frag

__device__ __forceinline__ float gelu_f(float x) {
    return 0.5f * x * (1.0f + tanhf(0.7978845608028654f * (x + 0.044715f * x * x * x)));
}

__device__ __forceinline__ bf16_t f2bf(float f) {
    unsigned u = __float_as_uint(f);
    unsigned r = (u + 0x7FFFu + ((u >> 16) & 1u)) >> 16;   // RNE
    return (bf16_t)r;
}
__device__ __forceinline__ float bf2f(bf16_t h) { return __uint_as_float(((unsigned)h) << 16); }
__device__ __forceinline__ float bfl(unsigned x) { return __uint_as_float(x << 16); }
__device__ __forceinline__ float bfh(unsigned x) { return __uint_as_float(x & 0xFFFF0000u); }

// ---------------- CSR build (counting sort by dst) ----------------
__global__ void k_zero32(unsigned* p, int n) {
    int i = blockIdx.x * 256 + threadIdx.x;
    if (i < n) p[i] = 0u;
}

__global__ void k_hist(const int* __restrict__ dst, int* __restrict__ deg) {
    int i = blockIdx.x * 256 + threadIdx.x;
    if (i < N_EDGES) atomicAdd(&deg[dst[i]], 1);
}

__global__ void k_scan1(const int* __restrict__ deg, int* __restrict__ rowptr, int* __restrict__ bsum) {
    __shared__ int sd[1024];
    int gi = blockIdx.x * 1024 + threadIdx.x;
    int v = (gi < N_NODES) ? deg[gi] : 0;
    sd[threadIdx.x] = v;
    __syncthreads();
    for (int off = 1; off < 1024; off <<= 1) {
        int t2 = (threadIdx.x >= (unsigned)off) ? sd[threadIdx.x - off] : 0;
        __syncthreads();
        sd[threadIdx.x] += t2;
        __syncthreads();
    }
    if (gi < N_NODES) rowptr[gi] = sd[threadIdx.x] - v;  // block-local exclusive
    if (threadIdx.x == 1023) bsum[blockIdx.x] = sd[1023];
}

__global__ void k_scan2(const int* __restrict__ bsum, int* __restrict__ boff, int nb) {
    if (threadIdx.x == 0 && blockIdx.x == 0) {
        int run = 0;
        for (int b = 0; b < nb; b++) { boff[b] = run; run += bsum[b]; }
    }
}

__global__ void k_scan3(int* __restrict__ rowptr, const int* __restrict__ boff) {
    int gi = blockIdx.x * 1024 + threadIdx.x;
    if (gi < N_NODES) rowptr[gi] += boff[blockIdx.x];
    if (gi == 0) rowptr[N_NODES] = N_EDGES;
}

__global__ void k_copy(const int* __restrict__ a, int* __restrict__ b) {
    int i = blockIdx.x * 256 + threadIdx.x;
    if (i < N_NODES) b[i] = a[i];
}

__global__ void k_scatter(const int* __restrict__ dst, int* __restrict__ cursor, int* __restrict__ eidx) {
    int i = blockIdx.x * 256 + threadIdx.x;
    if (i < N_EDGES) {
        int p = atomicAdd(&cursor[dst[i]], 1);
        eidx[p] = i;
    }
}

// Gather all per-edge fields into dst-sorted order so downstream kernels are linear.
__global__ void k_sortgather(
    const int* __restrict__ eidx, const int* __restrict__ src, const int* __restrict__ dst,
    const int* __restrict__ etype, const int* __restrict__ erid,
    const float* __restrict__ att_rc, const float* __restrict__ att_rp,
    int* __restrict__ src_s, int* __restrict__ dst_s,
    int* __restrict__ etype_s, int* __restrict__ erid_s,
    float* __restrict__ rc_s, float* __restrict__ rp_s)
{
    int i = blockIdx.x * 256 + threadIdx.x;
    if (i < N_EDGES) {
        int e = eidx[i];
        src_s[i] = src[e];
        dst_s[i] = dst[e];
        etype_s[i] = etype[e];
        erid_s[i] = erid[e];
        rc_s[2 * i] = att_rc[2 * e];
        rc_s[2 * i + 1] = att_rc[2 * e + 1];
        rp_s[3 * i] = att_rp[3 * e];
        rp_s[3 * i + 1] = att_rp[3 * e + 1];
        rp_s[3 * i + 2] = att_rp[3 * e + 2];
    }
}

// All weight transposes to bf16, k-contiguous rows (MFMA A-operand friendly).
__global__ void k_wprep(const float* __restrict__ Wfij, const float* __restrict__ Wni,
                        const float* __restrict__ Wnj, const float* __restrict__ Wnode,
                        const float* __restrict__ W1, const float* __restrict__ W2,
                        bf16_t* __restrict__ WT, bf16_t* __restrict__ W3T,
                        bf16_t* __restrict__ W1T, bf16_t* __restrict__ W2T)
{
    int idx = blockIdx.x * 256 + threadIdx.x;
    if (idx >= NLAYER * 57344) return;
    int l = idx / 57344, r = idx % 57344;
    if (r < 8192) {
        int n = r >> 6, k = r & 63;
        WT[l * 8192 + r] = f2bf(Wfij[l * 8192 + k * 128 + n]);
    } else if (r < 32768) {
        int q = r - 8192; int c = q >> 6, k = q & 63;
        const float* src = (c < 128) ? Wni : (c < 256) ? Wnj : Wnode;
        W3T[l * 24576 + q] = f2bf(src[l * 8192 + k * 128 + (c & 127)]);
    } else if (r < 49152) {
        int q = r - 32768; int n = q >> 7, k = q & 127;
        W1T[l * 16384 + q] = f2bf(W1[l * 16384 + k * 128 + n]);
    } else {
        int q = r - 49152; int j = q >> 7, k = q & 127;
        W2T[l * 8192 + q] = f2bf(W2[l * 8192 + k * 64 + j]);
    }
}

// ---------------- feature encoder: h0 = gelu(feat@W1+b1)@W2+b2 ----------------
__global__ __launch_bounds__(256) void k_fe(
    const float* __restrict__ feat, const float* __restrict__ W1, const float* __restrict__ b1,
    const float* __restrict__ W2, const float* __restrict__ b2,
    float* __restrict__ h, bf16_t* __restrict__ hb, float* __restrict__ out)
{
    __shared__ float hid[4][64];
    int w = threadIdx.x >> 6, lane = threadIdx.x & 63;
    int n = blockIdx.x * 4 + w;  // N divisible by 4
    float a = b1[lane];
#pragma unroll 8
    for (int k = 0; k < 32; k++) a = fmaf(feat[n * 32 + k], W1[k * 64 + lane], a);
    hid[w][lane] = gelu_f(a);
    __syncthreads();
    float o = b2[lane];
#pragma unroll 8
    for (int k = 0; k < 64; k++) o = fmaf(hid[w][k], W2[k * 64 + lane], o);
    h[n * 64 + lane] = o;
    hb[n * 64 + lane] = f2bf(o);
    out[n * 704 + 32 + lane] = o;
    if (lane < 32) out[n * 704 + lane] = feat[n * 32 + lane];
}

// ---------------- s = h @ [W_ni | W_nj | W_node(+b)] -> [NPAD,384] bf16, MFMA ----------------
__global__ __launch_bounds__(256) void k_node3(
    const bf16_t* __restrict__ hb, const bf16_t* __restrict__ W3T,
    const float* __restrict__ bnode, bf16_t* __restrict__ s)
{
    __shared__ __align__(16) bf16_t hbS[32 * 72];
    const int t = threadIdx.x;
    const int wave = t >> 6, lane = t & 63, l16 = lane & 15, quad = lane >> 4;
    const int n0 = blockIdx.x * 32;
    {   // stage hb tile: 32 rows x 128B
        int r = t >> 3, sg = t & 7;
        *(s16x8*)(hbS + r * 72 + sg * 8) = *(const s16x8*)(hb + (size_t)(n0 + r) * 64 + sg * 8);
    }
    __syncthreads();
    const int ng = wave & 1, ch = wave >> 1;
    const s16x8 B0 = *(const s16x8*)(hbS + (ng * 16 + l16) * 72 + quad * 8);
    const s16x8 B1 = *(const s16x8*)(hbS + (ng * 16 + l16) * 72 + 32 + quad * 8);
    const int node = n0 + ng * 16 + l16;
#pragma unroll
    for (int nt = 0; nt < 12; nt++) {
        int c0 = ch * 192 + nt * 16;
        const s16x8 A0 = *(const s16x8*)(W3T + (size_t)(c0 + l16) * 64 + quad * 8);
        const s16x8 A1 = *(const s16x8*)(W3T + (size_t)(c0 + l16) * 64 + 32 + quad * 8);
        f32x4 acc = {0.f, 0.f, 0.f, 0.f};
        acc = __builtin_amdgcn_mfma_f32_16x16x32_bf16(A0, B0, acc, 0, 0, 0);
        acc = __builtin_amdgcn_mfma_f32_16x16x32_bf16(A1, B1, acc, 0, 0, 0);
        int cb = c0 + quad * 4;
        float4 bv = make_float4(0.f, 0.f, 0.f, 0.f);
        if (cb >= 256) bv = *(const float4*)(bnode + cb - 256);
        ushort4 o;
        o.x = f2bf(acc[0] + bv.x);
        o.y = f2bf(acc[1] + bv.y);
        o.z = f2bf(acc[2] + bv.z);
        o.w = f2bf(acc[3] + bv.w);
        *(ushort4*)(s + (size_t)node * 384 + cb) = o;
    }
}

// ---------------- fused edge kernel, MFMA + direct per-lane SND gather ----------------
// One 32-edge tile per block. Lane (l16,quad) of wave (eg,head) owns edge e=eg*16+l16,
// wcols head*64+mt*16+quad*4..+3 (C layout). Epilogue terms gathered directly as
// ushort4 from s at the exact cols (includes head offset — fixes R4/R5 head-1 bug);
// gathers issued at kernel top to overlap embed VALU + MFMA.
__global__ __launch_bounds__(256) void k_edge(
    const bf16_t* __restrict__ s, const bf16_t* __restrict__ WT,
    const float* __restrict__ attn,
    const float* __restrict__ type_emb, const float* __restrict__ rid_emb,
    const float* __restrict__ rcW, const float* __restrict__ rcb,
    const float* __restrict__ rpW, const float* __restrict__ rpb,
    const float* __restrict__ rc_s, const float* __restrict__ rp_s,
    const int* __restrict__ etype_s, const int* __restrict__ erid_s,
    const int* __restrict__ src_s, const int* __restrict__ dst_s,
    float* __restrict__ evals)
{
    __shared__ __align__(16) bf16_t efA[32 * 72];
    const int t = threadIdx.x;
    const int wave = t >> 6, lane = t & 63;
    const int l16 = lane & 15, quad = lane >> 4;
    const int eg = wave & 1, head = wave >> 1;
    const int eb = blockIdx.x * 32;
    const int e = eg * 16 + l16;
    const int gi = eb + e;

    // Epilogue gathers first: 4+4 ushort4 (8B) from the two s rows this lane needs.
    const int srcn = src_s[gi], dstn = dst_s[gi];
    ushort4 u4[4], v4[4];
#pragma unroll
    for (int mt = 0; mt < 4; mt++) {
        const int c = head * 64 + mt * 16 + quad * 4;
        u4[mt] = *(const ushort4*)(s + (size_t)srcn * 384 + c);
        v4[mt] = *(const ushort4*)(s + (size_t)dstn * 384 + 128 + c);
    }

    // W^T fragments (A operand) + attn coefficients (C layout).
    s16x8 Aw[4][2];
    float4 att4[4];
#pragma unroll
    for (int mt = 0; mt < 4; mt++) {
        const bf16_t* wrow = WT + (head * 64 + mt * 16 + l16) * 64 + quad * 8;
        Aw[mt][0] = *(const s16x8*)(wrow);
        Aw[mt][1] = *(const s16x8*)(wrow + 32);
        att4[mt] = *(const float4*)(attn + head * 64 + mt * 16 + quad * 4);
    }

    {   // Phase A: edge embedding -> efA (thread t: edge t&31, 8 k's, bf16)
        int el = t & 31, kg = (t >> 5) * 8;
        int i = eb + el;
        int et = etype_s[i] * 64, er = erid_s[i] * 64;
        float rc0 = rc_s[i * 2 + 0], rc1 = rc_s[i * 2 + 1];
        float rp0 = rp_s[i * 3 + 0], rp1 = rp_s[i * 3 + 1], rp2 = rp_s[i * 3 + 2];
        bf16_t tmp[8];
#pragma unroll
        for (int kk = 0; kk < 8; kk++) {
            int k = kg + kk;
            float v = type_emb[et + k] + rid_emb[er + k] + rcb[k] + rpb[k];
            v = fmaf(rc0, rcW[k], v);
            v = fmaf(rc1, rcW[64 + k], v);
            v = fmaf(rp0, rpW[k], v);
            v = fmaf(rp1, rpW[64 + k], v);
            v = fmaf(rp2, rpW[128 + k], v);
            tmp[kk] = f2bf(v);
        }
        *(s16x8*)(&efA[el * 72 + kg]) = *(const s16x8*)tmp;
    }
    __syncthreads();

    // MFMA: B frags = ef rows, K-steps k=quad*8+j (+32).
    const s16x8 B0 = *(const s16x8*)(&efA[e * 72 + quad * 8]);
    const s16x8 B1 = *(const s16x8*)(&efA[e * 72 + 32 + quad * 8]);
    f32x4 acc[4];
#pragma unroll
    for (int mt = 0; mt < 4; mt++) {
        f32x4 a = {0.f, 0.f, 0.f, 0.f};
        a = __builtin_amdgcn_mfma_f32_16x16x32_bf16(Aw[mt][0], B0, a, 0, 0, 0);
        a = __builtin_amdgcn_mfma_f32_16x16x32_bf16(Aw[mt][1], B1, a, 0, 0, 0);
        acc[mt] = a;
    }

    // Epilogue: f = acc + s_ni[src] + s_nj[dst]; leaky; dot attn; reduce over quads.
    float p = 0.f;
#pragma unroll
    for (int mt = 0; mt < 4; mt++) {
        float f0 = acc[mt][0] + bf2f(u4[mt].x) + bf2f(v4[mt].x);
        float f1 = acc[mt][1] + bf2f(u4[mt].y) + bf2f(v4[mt].y);
        float f2 = acc[mt][2] + bf2f(u4[mt].z) + bf2f(v4[mt].z);
        float f3 = acc[mt][3] + bf2f(u4[mt].w) + bf2f(v4[mt].w);
        f0 = (f0 >= 0.f) ? f0 : 0.2f * f0;
        f1 = (f1 >= 0.f) ? f1 : 0.2f * f1;
        f2 = (f2 >= 0.f) ? f2 : 0.2f * f2;
        f3 = (f3 >= 0.f) ? f3 : 0.2f * f3;
        p = fmaf(f0, att4[mt].x, p);
        p = fmaf(f1, att4[mt].y, p);
        p = fmaf(f2, att4[mt].z, p);
        p = fmaf(f3, att4[mt].w, p);
    }
    p += __shfl_xor(p, 16);
    p += __shfl_xor(p, 32);
    if (quad == 0) evals[gi * 2 + head] = p;
}

// ---------------- per-dst softmax + aggregation -> aggb bf16 ----------------
__global__ __launch_bounds__(256) void k_soft_agg(
    const int* __restrict__ rowptr, const int* __restrict__ src_s,
    const float* __restrict__ evals, const bf16_t* __restrict__ s,
    unsigned* __restrict__ aggb)   // [NPAD][64] uints = [NPAD][128] bf16
{
    int lane = threadIdx.x & 63;
    int wid = (blockIdx.x * 256 + threadIdx.x) >> 6;
    int nw = (gridDim.x * 256) >> 6;
    const int h1 = (lane >= 32) ? 1 : 0;
    const int half = lane & 31;
    for (int n = wid; n < N_NODES; n += nw) {
        int r0 = rowptr[n], r1 = rowptr[n + 1];
        unsigned* aout = aggb + (size_t)n * 64 + lane;
        if (r0 == r1) { *aout = 0u; continue; }
        float mm = -1e30f;
        for (int i = r0 + half; i < r1; i += 32) mm = fmaxf(mm, evals[2 * i + h1]);
#pragma unroll
        for (int off = 1; off < 32; off <<= 1) mm = fmaxf(mm, __shfl_xor(mm, off));
        float z = 0.f;
        for (int i = r0 + half; i < r1; i += 32) z += expf(evals[2 * i + h1] - mm);
#pragma unroll
        for (int off = 1; off < 32; off <<= 1) z += __shfl_xor(z, off);
        float rz = 1.f / z;
        float acc0 = 0.f, acc1 = 0.f;
        // batched x16 to keep many gathers in flight
        for (int i = r0; i < r1; i += 16) {
            int cnt = r1 - i;
            unsigned cc[16]; float ww[16];
#pragma unroll
            for (int j = 0; j < 16; j++) {
                if (j < cnt) {
                    cc[j] = *(const unsigned*)(s + (size_t)src_s[i + j] * 384 + 256 + 2 * lane);
                    ww[j] = expf(evals[2 * (i + j) + h1] - mm) * rz;
                } else { cc[j] = 0u; ww[j] = 0.f; }
            }
#pragma unroll
            for (int j = 0; j < 16; j++) {
                acc0 = fmaf(ww[j], bfl(cc[j]), acc0);
                acc1 = fmaf(ww[j], bfh(cc[j]), acc1);
            }
        }
        *aout = (unsigned)f2bf(acc0) | ((unsigned)f2bf(acc1) << 16);
    }
}

// ---------------- node MLP + residual, MFMA: h' = gelu(agg@W1+b1)@W2+b2 + h ----------------
__global__ __launch_bounds__(256) void k_mlp(
    const bf16_t* __restrict__ aggb, const bf16_t* __restrict__ W1T, const float* __restrict__ b1,
    const bf16_t* __restrict__ W2T, const float* __restrict__ b2,
    const float* __restrict__ hin, float* __restrict__ hout, bf16_t* __restrict__ houtb,
    float* __restrict__ out, int col0)
{
    __shared__ __align__(16) bf16_t aggS[32 * 136];
    __shared__ __align__(16) bf16_t hidS[32 * 136];
    const int t = threadIdx.x;
    const int wave = t >> 6, lane = t & 63, l16 = lane & 15, quad = lane >> 4;
    const int n0 = blockIdx.x * 32;
    {   // stage agg tile: 32 rows x 256B (32B per thread)
        int r = t >> 3, sg = t & 7;
        *(s16x8*)(aggS + r * 136 + sg * 16) =
            *(const s16x8*)(aggb + (size_t)(n0 + r) * 128 + sg * 16);
        *(s16x8*)(aggS + r * 136 + sg * 16 + 8) =
            *(const s16x8*)(aggb + (size_t)(n0 + r) * 128 + sg * 16 + 8);
    }
    __syncthreads();
    const int ng = wave & 1, nh = wave >> 1;
    const int node = n0 + ng * 16 + l16;
    {   // GEMM1 + gelu -> hidS
        const bf16_t* brow = aggS + (ng * 16 + l16) * 136 + quad * 8;
        s16x8 B[4];
#pragma unroll
        for (int ks = 0; ks < 4; ks++) B[ks] = *(const s16x8*)(brow + ks * 32);
#pragma unroll
        for (int nt = 0; nt < 4; nt++) {
            int nb = nh * 64 + nt * 16;
            f32x4 acc = {0.f, 0.f, 0.f, 0.f};
#pragma unroll
            for (int ks = 0; ks < 4; ks++) {
                const s16x8 A = *(const s16x8*)(W1T + (size_t)(nb + l16) * 128 + ks * 32 + quad * 8);
                acc = __builtin_amdgcn_mfma_f32_16x16x32_bf16(A, B[ks], acc, 0, 0, 0);
            }
            const float4 bv = *(const float4*)(b1 + nb + quad * 4);
            ushort4 o;
            o.x = f2bf(gelu_f(acc[0] + bv.x));
            o.y = f2bf(gelu_f(acc[1] + bv.y));
            o.z = f2bf(gelu_f(acc[2] + bv.z));
            o.w = f2bf(gelu_f(acc[3] + bv.w));
            *(ushort4*)(hidS + (ng * 16 + l16) * 136 + nb + quad * 4) = o;
        }
    }
    __syncthreads();
    {   // GEMM2 + bias + residual -> hout/houtb/out
        const int jh = wave >> 1;
        const bf16_t* hrow = hidS + (ng * 16 + l16) * 136 + quad * 8;
        s16x8 H[4];
#pragma unroll
        for (int ks = 0; ks < 4; ks++) H[ks] = *(const s16x8*)(hrow + ks * 32);
#pragma unroll
        for (int jt = 0; jt < 2; jt++) {
            int jb = jh * 32 + jt * 16;
            f32x4 acc = {0.f, 0.f, 0.f, 0.f};
#pragma unroll
            for (int ks = 0; ks < 4; ks++) {
                const s16x8 A = *(const s16x8*)(W2T + (size_t)(jb + l16) * 128 + ks * 32 + quad * 8);
                acc = __builtin_amdgcn_mfma_f32_16x16x32_bf16(A, H[ks], acc, 0, 0, 0);
            }
            int j0 = jb + quad * 4;
            const float4 bv = *(const float4*)(b2 + j0);
            const float4 hv = *(const float4*)(hin + (size_t)node * 64 + j0);
            float4 v;
            v.x = acc[0] + bv.x + hv.x;
            v.y = acc[1] + bv.y + hv.y;
            v.z = acc[2] + bv.z + hv.z;
            v.w = acc[3] + bv.w + hv.w;
            *(float4*)(hout + (size_t)node * 64 + j0) = v;
            ushort4 ob;
            ob.x = f2bf(v.x); ob.y = f2bf(v.y); ob.z = f2bf(v.z); ob.w = f2bf(v.w);
            *(ushort4*)(houtb + (size_t)node * 64 + j0) = ob;
            if (node < N_NODES)
                *(float4*)(out + (size_t)node * 704 + col0 + j0) = v;
        }
    }
}

// ---------------- graph max pooling over node_emb cols 0..351 ----------------
__device__ __forceinline__ unsigned fmap(float v) {
    unsigned u = __float_as_uint(v);
    return (u & 0x80000000u) ? ~u : (u | 0x80000000u);
}

__global__ __launch_bounds__(384) void k_colmax(const float* __restrict__ out, unsigned* __restrict__ gmax) {
    int c = threadIdx.x;
    if (c >= 352) return;
    float m = -1e30f;
    for (int n = blockIdx.x; n < N_NODES; n += gridDim.x)
        m = fmaxf(m, out[(size_t)n * 704 + c]);
    atomicMax(gmax + c, fmap(m));
}

__global__ __launch_bounds__(384) void k_bcast(const unsigned* __restrict__ gmax, float* __restrict__ out) {
    int c = threadIdx.x;
    if (c >= 352) return;
    unsigned u = gmax[c];
    u = (u & 0x80000000u) ? (u ^ 0x80000000u) : ~u;
    float v = __uint_as_float(u);
    for (int n = blockIdx.x; n < N_NODES; n += gridDim.x)
        out[(size_t)n * 704 + 352 + c] = v;
}

// ---------------- host launcher ----------------
extern "C" void kernel_launch(void* const* d_in, const int* in_sizes, int n_in,
                              void* d_out, int out_size, void* d_ws, size_t ws_size,
                              hipStream_t stream)
{
    (void)in_sizes; (void)n_in; (void)out_size; (void)ws_size;
    const float* feat     = (const float*)d_in[0];
    const float* att_rc   = (const float*)d_in[1];
    const float* att_rp   = (const float*)d_in[2];
    const float* type_emb = (const float*)d_in[3];
    const float* rid_emb  = (const float*)d_in[4];
    const float* rc_W     = (const float*)d_in[5];
    const float* rc_b     = (const float*)d_in[6];
    const float* rp_W     = (const float*)d_in[7];
    const float* rp_b     = (const float*)d_in[8];
    const float* fe_W1    = (const float*)d_in[9];
    const float* fe_b1    = (const float*)d_in[10];
    const float* fe_W2    = (const float*)d_in[11];
    const float* fe_b2    = (const float*)d_in[12];
    const float* W_ni     = (const float*)d_in[13];
    const float* W_nj     = (const float*)d_in[14];
    const float* W_fij    = (const float*)d_in[15];
    const float* W_node   = (const float*)d_in[16];
    const float* b_node   = (const float*)d_in[17];
    const float* attn     = (const float*)d_in[18];
    const float* mlp_W1   = (const float*)d_in[19];
    const float* mlp_b1   = (const float*)d_in[20];
    const float* mlp_W2   = (const float*)d_in[21];
    const float* mlp_b2   = (const float*)d_in[22];
    const int* src   = (const int*)d_in[23];
    const int* dst   = (const int*)d_in[24];
    const int* etype = (const int*)d_in[25];
    const int* erid  = (const int*)d_in[26];
    float* out = (float*)d_out;

    // Workspace layout (byte cursor, all chunks 16B aligned).
    char* cur = (char*)d_ws;
    auto alloc = [&](size_t bytes) { char* p = cur; cur += (bytes + 15) & ~(size_t)15; return p; };
    float* h_a    = (float*)alloc((size_t)NPAD * 64 * 4);
    float* h_b    = (float*)alloc((size_t)NPAD * 64 * 4);
    bf16_t* hb_a  = (bf16_t*)alloc((size_t)NPAD * 64 * 2);
    bf16_t* hb_b  = (bf16_t*)alloc((size_t)NPAD * 64 * 2);
    bf16_t* s     = (bf16_t*)alloc((size_t)NPAD * 384 * 2);
    float* ev     = (float*)alloc((size_t)N_EDGES * 2 * 4);
    bf16_t* aggb  = (bf16_t*)alloc((size_t)NPAD * 128 * 2);
    int* deg     = (int*)alloc((size_t)N_NODES * 4);
    int* rowptr  = (int*)alloc((size_t)(N_NODES + 1) * 4);
    int* cursor  = (int*)alloc((size_t)N_NODES * 4);
    int* eidx    = (int*)alloc((size_t)N_EDGES * 4);
    int* src_s   = (int*)alloc((size_t)N_EDGES * 4);
    int* dst_s   = (int*)alloc((size_t)N_EDGES * 4);
    int* etype_s = (int*)alloc((size_t)N_EDGES * 4);
    int* erid_s  = (int*)alloc((size_t)N_EDGES * 4);
    float* rc_s  = (float*)alloc((size_t)N_EDGES * 2 * 4);
    float* rp_s  = (float*)alloc((size_t)N_EDGES * 3 * 4);
    bf16_t* WT   = (bf16_t*)alloc((size_t)NLAYER * 128 * 64 * 2);
    bf16_t* W3T  = (bf16_t*)alloc((size_t)NLAYER * 384 * 64 * 2);
    bf16_t* W1T  = (bf16_t*)alloc((size_t)NLAYER * 128 * 128 * 2);
    bf16_t* W2T  = (bf16_t*)alloc((size_t)NLAYER * 64 * 128 * 2);
    int* bsum    = (int*)alloc(64 * 4);
    int* boff    = (int*)alloc(64 * 4);
    unsigned* gmax = (unsigned*)alloc(352 * 4);

    const int NB = (N_NODES + 1023) / 1024;  // 49

    k_zero32<<<(N_NODES + 255) / 256, 256, 0, stream>>>((unsigned*)deg, N_NODES);
    k_zero32<<<2, 256, 0, stream>>>(gmax, 352);
    k_hist<<<N_EDGES / 256, 256, 0, stream>>>(dst, deg);
    k_scan1<<<NB, 1024, 0, stream>>>(deg, rowptr, bsum);
    k_scan2<<<1, 64, 0, stream>>>(bsum, boff, NB);
    k_scan3<<<NB, 1024, 0, stream>>>(rowptr, boff);
    k_copy<<<(N_NODES + 255) / 256, 256, 0, stream>>>(rowptr, cursor);
    k_scatter<<<N_EDGES / 256, 256, 0, stream>>>(dst, cursor, eidx);
    k_sortgather<<<N_EDGES / 256, 256, 0, stream>>>(eidx, src, dst, etype, erid, att_rc, att_rp,
                                                    src_s, dst_s, etype_s, erid_s, rc_s, rp_s);
    k_wprep<<<(NLAYER * 57344 + 255) / 256, 256, 0, stream>>>(
        W_fij, W_ni, W_nj, W_node, mlp_W1, mlp_W2, WT, W3T, W1T, W2T);
    k_fe<<<N_NODES / 4, 256, 0, stream>>>(feat, fe_W1, fe_b1, fe_W2, fe_b2, h_a, hb_a, out);

    float* hc = h_a;  bf16_t* hbc = hb_a;
    float* hn = h_b;  bf16_t* hbn = hb_b;
    for (int l = 0; l < NLAYER; l++) {
        k_node3<<<NPAD / 32, 256, 0, stream>>>(hbc, W3T + (size_t)l * 384 * 64, b_node + l * 128, s);
        k_edge<<<N_EDGES / 32, 256, 0, stream>>>(s, WT + l * 128 * 64, attn + l * 128,
                                                 type_emb, rid_emb, rc_W, rc_b, rp_W, rp_b,
                                                 rc_s, rp_s, etype_s, erid_s, src_s, dst_s, ev);
        k_soft_agg<<<8192, 256, 0, stream>>>(rowptr, src_s, ev, s, (unsigned*)aggb);
        k_mlp<<<NPAD / 32, 256, 0, stream>>>(aggb, W1T + (size_t)l * 128 * 128, mlp_b1 + l * 128,
                                             W2T + (size_t)l * 64 * 128, mlp_b2 + l * 64,
                                             hc, hn, hbn, out, 32 + 64 * (l + 1));
        float* tf = hc; hc = hn; hn = tf;
        bf16_t* tb = hbc; hbc = hbn; hbn = tb;
    }
    k_colmax<<<512, 384, 0, stream>>>(out, gmax);
    k_bcast<<<512, 384, 0, stream>>>(gmax, out);
}

// Round 8
// 1436.015 us; speedup vs baseline: 1.2038x; 1.2038x over previous
//
#include <hip/hip_runtime.h>
#include <math.h>

// Problem constants (fixed by the reference).
#define N_NODES 50000
#define N_EDGES 640000   // divisible by 32 (20000 tiles) and 256
#define NLAYER  4
#define NPAD    50016    // N_NODES rounded up to 32

typedef unsigned short bf16_t;
typedef __attribute__((ext_vector_type(8))) short s16x8;   // 8 bf16 = 4 VGPR (MFMA A/B frag)
typedef __attribute__((ext_vector_type(4))) float f32x4;   // MFMA C/D frag

__device__ __forceinline__ float gelu_f(float x) {
    return 0.5f * x * (1.0f + tanhf(0.7978845608028654f * (x + 0.044715f * x * x * x)));
}

__device__ __forceinline__ bf16_t f2bf(float f) {
    unsigned u = __float_as_uint(f);
    unsigned r = (u + 0x7FFFu + ((u >> 16) & 1u)) >> 16;   // RNE
    return (bf16_t)r;
}
__device__ __forceinline__ float bf2f(bf16_t h) { return __uint_as_float(((unsigned)h) << 16); }
__device__ __forceinline__ float bfl(unsigned x) { return __uint_as_float(x << 16); }
__device__ __forceinline__ float bfh(unsigned x) { return __uint_as_float(x & 0xFFFF0000u); }

// ---------------- CSR build (counting sort by dst) ----------------
__global__ void k_zero32(unsigned* p, int n) {
    int i = blockIdx.x * 256 + threadIdx.x;
    if (i < n) p[i] = 0u;
}

__global__ void k_hist(const int* __restrict__ dst, int* __restrict__ deg) {
    int i = blockIdx.x * 256 + threadIdx.x;
    if (i < N_EDGES) atomicAdd(&deg[dst[i]], 1);
}

__global__ void k_scan1(const int* __restrict__ deg, int* __restrict__ rowptr, int* __restrict__ bsum) {
    __shared__ int sd[1024];
    int gi = blockIdx.x * 1024 + threadIdx.x;
    int v = (gi < N_NODES) ? deg[gi] : 0;
    sd[threadIdx.x] = v;
    __syncthreads();
    for (int off = 1; off < 1024; off <<= 1) {
        int t2 = (threadIdx.x >= (unsigned)off) ? sd[threadIdx.x - off] : 0;
        __syncthreads();
        sd[threadIdx.x] += t2;
        __syncthreads();
    }
    if (gi < N_NODES) rowptr[gi] = sd[threadIdx.x] - v;  // block-local exclusive
    if (threadIdx.x == 1023) bsum[blockIdx.x] = sd[1023];
}

__global__ void k_scan2(const int* __restrict__ bsum, int* __restrict__ boff, int nb) {
    if (threadIdx.x == 0 && blockIdx.x == 0) {
        int run = 0;
        for (int b = 0; b < nb; b++) { boff[b] = run; run += bsum[b]; }
    }
}

__global__ void k_scan3(int* __restrict__ rowptr, const int* __restrict__ boff) {
    int gi = blockIdx.x * 1024 + threadIdx.x;
    if (gi < N_NODES) rowptr[gi] += boff[blockIdx.x];
    if (gi == 0) rowptr[N_NODES] = N_EDGES;
}

__global__ void k_copy(const int* __restrict__ a, int* __restrict__ b) {
    int i = blockIdx.x * 256 + threadIdx.x;
    if (i < N_NODES) b[i] = a[i];
}

__global__ void k_scatter(const int* __restrict__ dst, int* __restrict__ cursor, int* __restrict__ eidx) {
    int i = blockIdx.x * 256 + threadIdx.x;
    if (i < N_EDGES) {
        int p = atomicAdd(&cursor[dst[i]], 1);
        eidx[p] = i;
    }
}

// Gather all per-edge fields into dst-sorted order so downstream kernels are linear.
__global__ void k_sortgather(
    const int* __restrict__ eidx, const int* __restrict__ src, const int* __restrict__ dst,
    const int* __restrict__ etype, const int* __restrict__ erid,
    const float* __restrict__ att_rc, const float* __restrict__ att_rp,
    int* __restrict__ src_s, int* __restrict__ dst_s,
    int* __restrict__ etype_s, int* __restrict__ erid_s,
    float* __restrict__ rc_s, float* __restrict__ rp_s)
{
    int i = blockIdx.x * 256 + threadIdx.x;
    if (i < N_EDGES) {
        int e = eidx[i];
        src_s[i] = src[e];
        dst_s[i] = dst[e];
        etype_s[i] = etype[e];
        erid_s[i] = erid[e];
        rc_s[2 * i] = att_rc[2 * e];
        rc_s[2 * i + 1] = att_rc[2 * e + 1];
        rp_s[3 * i] = att_rp[3 * e];
        rp_s[3 * i + 1] = att_rp[3 * e + 1];
        rp_s[3 * i + 2] = att_rp[3 * e + 2];
    }
}

// All weight transposes to bf16, k-contiguous rows (MFMA A-operand friendly).
__global__ void k_wprep(const float* __restrict__ Wfij, const float* __restrict__ Wni,
                        const float* __restrict__ Wnj, const float* __restrict__ Wnode,
                        const float* __restrict__ W1, const float* __restrict__ W2,
                        bf16_t* __restrict__ WT, bf16_t* __restrict__ W3T,
                        bf16_t* __restrict__ W1T, bf16_t* __restrict__ W2T)
{
    int idx = blockIdx.x * 256 + threadIdx.x;
    if (idx >= NLAYER * 57344) return;
    int l = idx / 57344, r = idx % 57344;
    if (r < 8192) {
        int n = r >> 6, k = r & 63;
        WT[l * 8192 + r] = f2bf(Wfij[l * 8192 + k * 128 + n]);
    } else if (r < 32768) {
        int q = r - 8192; int c = q >> 6, k = q & 63;
        const float* src = (c < 128) ? Wni : (c < 256) ? Wnj : Wnode;
        W3T[l * 24576 + q] = f2bf(src[l * 8192 + k * 128 + (c & 127)]);
    } else if (r < 49152) {
        int q = r - 32768; int n = q >> 7, k = q & 127;
        W1T[l * 16384 + q] = f2bf(W1[l * 16384 + k * 128 + n]);
    } else {
        int q = r - 49152; int j = q >> 7, k = q & 127;
        W2T[l * 8192 + q] = f2bf(W2[l * 8192 + k * 64 + j]);
    }
}

// ---------------- feature encoder: h0 = gelu(feat@W1+b1)@W2+b2 ----------------
__global__ __launch_bounds__(256) void k_fe(
    const float* __restrict__ feat, const float* __restrict__ W1, const float* __restrict__ b1,
    const float* __restrict__ W2, const float* __restrict__ b2,
    float* __restrict__ h, bf16_t* __restrict__ hb, float* __restrict__ out)
{
    __shared__ float hid[4][64];
    int w = threadIdx.x >> 6, lane = threadIdx.x & 63;
    int n = blockIdx.x * 4 + w;  // N divisible by 4
    float a = b1[lane];
#pragma unroll 8
    for (int k = 0; k < 32; k++) a = fmaf(feat[n * 32 + k], W1[k * 64 + lane], a);
    hid[w][lane] = gelu_f(a);
    __syncthreads();
    float o = b2[lane];
#pragma unroll 8
    for (int k = 0; k < 64; k++) o = fmaf(hid[w][k], W2[k * 64 + lane], o);
    h[n * 64 + lane] = o;
    hb[n * 64 + lane] = f2bf(o);
    out[n * 704 + 32 + lane] = o;
    if (lane < 32) out[n * 704 + lane] = feat[n * 32 + lane];
}

// ---------------- s = h @ [W_ni | W_nj | W_node(+b)] -> [NPAD,384] bf16, MFMA ----------------
__global__ __launch_bounds__(256) void k_node3(
    const bf16_t* __restrict__ hb, const bf16_t* __restrict__ W3T,
    const float* __restrict__ bnode, bf16_t* __restrict__ s)
{
    __shared__ __align__(16) bf16_t hbS[32 * 72];
    const int t = threadIdx.x;
    const int wave = t >> 6, lane = t & 63, l16 = lane & 15, quad = lane >> 4;
    const int n0 = blockIdx.x * 32;
    {   // stage hb tile: 32 rows x 128B
        int r = t >> 3, sg = t & 7;
        *(s16x8*)(hbS + r * 72 + sg * 8) = *(const s16x8*)(hb + (size_t)(n0 + r) * 64 + sg * 8);
    }
    __syncthreads();
    const int ng = wave & 1, ch = wave >> 1;
    const s16x8 B0 = *(const s16x8*)(hbS + (ng * 16 + l16) * 72 + quad * 8);
    const s16x8 B1 = *(const s16x8*)(hbS + (ng * 16 + l16) * 72 + 32 + quad * 8);
    const int node = n0 + ng * 16 + l16;
#pragma unroll
    for (int nt = 0; nt < 12; nt++) {
        int c0 = ch * 192 + nt * 16;
        const s16x8 A0 = *(const s16x8*)(W3T + (size_t)(c0 + l16) * 64 + quad * 8);
        const s16x8 A1 = *(const s16x8*)(W3T + (size_t)(c0 + l16) * 64 + 32 + quad * 8);
        f32x4 acc = {0.f, 0.f, 0.f, 0.f};
        acc = __builtin_amdgcn_mfma_f32_16x16x32_bf16(A0, B0, acc, 0, 0, 0);
        acc = __builtin_amdgcn_mfma_f32_16x16x32_bf16(A1, B1, acc, 0, 0, 0);
        int cb = c0 + quad * 4;
        float4 bv = make_float4(0.f, 0.f, 0.f, 0.f);
        if (cb >= 256) bv = *(const float4*)(bnode + cb - 256);
        ushort4 o;
        o.x = f2bf(acc[0] + bv.x);
        o.y = f2bf(acc[1] + bv.y);
        o.z = f2bf(acc[2] + bv.z);
        o.w = f2bf(acc[3] + bv.w);
        *(ushort4*)(s + (size_t)node * 384 + cb) = o;
    }
}

// ---------------- fused edge kernel, MFMA + double-buffered pipelined staging ----------------
// Persistent loop over 32-edge tiles (R5 structure). Tile i+1's global loads (edge scalars +
// coalesced uint4 s-row gathers) are issued into registers BEFORE computing tile i, then
// written to the alternate LDS buffer after compute — one barrier per tile, gather latency
// overlaps MFMA+epilogue. Epilogue reads SND at head*64 offset (fixes R4/R5 head-1 bug).
__global__ __launch_bounds__(256) void k_edge(
    const bf16_t* __restrict__ s, const bf16_t* __restrict__ WT,
    const float* __restrict__ attn,
    const float* __restrict__ type_emb, const float* __restrict__ rid_emb,
    const float* __restrict__ rcW, const float* __restrict__ rcb,
    const float* __restrict__ rpW, const float* __restrict__ rpb,
    const float* __restrict__ rc_s, const float* __restrict__ rp_s,
    const int* __restrict__ etype_s, const int* __restrict__ erid_s,
    const int* __restrict__ src_s, const int* __restrict__ dst_s,
    float* __restrict__ evals)
{
    __shared__ __align__(16) bf16_t efA[2][32 * 72];    // [buf][edge][k]
    __shared__ __align__(16) bf16_t SND[2][32 * 136];   // [buf][edge][col]
    const int t = threadIdx.x;
    const int wave = t >> 6, lane = t & 63;
    const int l16 = lane & 15, quad = lane >> 4;
    const int eg = wave & 1, head = wave >> 1;

    // Loop-invariant: W^T fragments (A operand) + attn coefficients (C layout).
    s16x8 Aw[4][2];
    float4 att4[4];
#pragma unroll
    for (int mt = 0; mt < 4; mt++) {
        const bf16_t* wrow = WT + (head * 64 + mt * 16 + l16) * 64 + quad * 8;
        Aw[mt][0] = *(const s16x8*)(wrow);
        Aw[mt][1] = *(const s16x8*)(wrow + 32);
        att4[mt] = *(const float4*)(attn + head * 64 + mt * 16 + quad * 4);
    }

    // Staging roles.
    const int elA = t & 31, kg = (t >> 5) * 8;            // embed: edge elA, 8 k's
    const int eA0 = (2 * t) >> 4, pA0 = (2 * t) & 15;     // SND chunk 0
    const int eA1 = (2 * t + 1) >> 4, pA1 = (2 * t + 1) & 15;  // SND chunk 1
    const int e = eg * 16 + l16;                           // compute: this lane's edge

    // Prefetch registers.
    int et, er; float rc0, rc1, rp0, rp1, rp2;
    uint4 U0, V0, U1, V1;

    auto issue = [&](int tl) {
        int ia = tl * 32 + elA;
        et = etype_s[ia] * 64; er = erid_s[ia] * 64;
        rc0 = rc_s[ia * 2]; rc1 = rc_s[ia * 2 + 1];
        rp0 = rp_s[ia * 3]; rp1 = rp_s[ia * 3 + 1]; rp2 = rp_s[ia * 3 + 2];
        int i0 = tl * 32 + eA0;
        U0 = *(const uint4*)(s + (size_t)src_s[i0] * 384 + pA0 * 8);
        V0 = *(const uint4*)(s + (size_t)dst_s[i0] * 384 + 128 + pA0 * 8);
        int i1 = tl * 32 + eA1;
        U1 = *(const uint4*)(s + (size_t)src_s[i1] * 384 + pA1 * 8);
        V1 = *(const uint4*)(s + (size_t)dst_s[i1] * 384 + 128 + pA1 * 8);
    };

    auto stage = [&](int b) {
        bf16_t tmp[8];
#pragma unroll
        for (int kk = 0; kk < 8; kk++) {
            int k = kg + kk;
            float v = type_emb[et + k] + rid_emb[er + k] + rcb[k] + rpb[k];
            v = fmaf(rc0, rcW[k], v);
            v = fmaf(rc1, rcW[64 + k], v);
            v = fmaf(rp0, rpW[k], v);
            v = fmaf(rp1, rpW[64 + k], v);
            v = fmaf(rp2, rpW[128 + k], v);
            tmp[kk] = f2bf(v);
        }
        *(s16x8*)(&efA[b][elA * 72 + kg]) = *(const s16x8*)tmp;
        bf16_t o[8];
        o[0] = f2bf(bfl(U0.x) + bfl(V0.x)); o[1] = f2bf(bfh(U0.x) + bfh(V0.x));
        o[2] = f2bf(bfl(U0.y) + bfl(V0.y)); o[3] = f2bf(bfh(U0.y) + bfh(V0.y));
        o[4] = f2bf(bfl(U0.z) + bfl(V0.z)); o[5] = f2bf(bfh(U0.z) + bfh(V0.z));
        o[6] = f2bf(bfl(U0.w) + bfl(V0.w)); o[7] = f2bf(bfh(U0.w) + bfh(V0.w));
        *(s16x8*)(&SND[b][eA0 * 136 + pA0 * 8]) = *(const s16x8*)o;
        o[0] = f2bf(bfl(U1.x) + bfl(V1.x)); o[1] = f2bf(bfh(U1.x) + bfh(V1.x));
        o[2] = f2bf(bfl(U1.y) + bfl(V1.y)); o[3] = f2bf(bfh(U1.y) + bfh(V1.y));
        o[4] = f2bf(bfl(U1.z) + bfl(V1.z)); o[5] = f2bf(bfh(U1.z) + bfh(V1.z));
        o[6] = f2bf(bfl(U1.w) + bfl(V1.w)); o[7] = f2bf(bfh(U1.w) + bfh(V1.w));
        *(s16x8*)(&SND[b][eA1 * 136 + pA1 * 8]) = *(const s16x8*)o;
    };

    const int NT = N_EDGES / 32;
    const int stride = gridDim.x;
    int tile = blockIdx.x;
    if (tile >= NT) return;

    issue(tile);
    stage(0);
    __syncthreads();
    int b = 0;

    while (tile < NT) {
        int next = tile + stride;
        if (next < NT) issue(next);

        // Compute current tile from buffer b.
        const s16x8 B0 = *(const s16x8*)(&efA[b][e * 72 + quad * 8]);
        const s16x8 B1 = *(const s16x8*)(&efA[b][e * 72 + 32 + quad * 8]);
        f32x4 acc[4];
#pragma unroll
        for (int mt = 0; mt < 4; mt++) {
            f32x4 a = {0.f, 0.f, 0.f, 0.f};
            a = __builtin_amdgcn_mfma_f32_16x16x32_bf16(Aw[mt][0], B0, a, 0, 0, 0);
            a = __builtin_amdgcn_mfma_f32_16x16x32_bf16(Aw[mt][1], B1, a, 0, 0, 0);
            acc[mt] = a;
        }
        float p = 0.f;
#pragma unroll
        for (int mt = 0; mt < 4; mt++) {
            const ushort4 sv = *(const ushort4*)(&SND[b][e * 136 + head * 64 + mt * 16 + quad * 4]);
            float f0 = acc[mt][0] + bf2f(sv.x);
            float f1 = acc[mt][1] + bf2f(sv.y);
            float f2 = acc[mt][2] + bf2f(sv.z);
            float f3 = acc[mt][3] + bf2f(sv.w);
            f0 = (f0 >= 0.f) ? f0 : 0.2f * f0;
            f1 = (f1 >= 0.f) ? f1 : 0.2f * f1;
            f2 = (f2 >= 0.f) ? f2 : 0.2f * f2;
            f3 = (f3 >= 0.f) ? f3 : 0.2f * f3;
            p = fmaf(f0, att4[mt].x, p);
            p = fmaf(f1, att4[mt].y, p);
            p = fmaf(f2, att4[mt].z, p);
            p = fmaf(f3, att4[mt].w, p);
        }
        p += __shfl_xor(p, 16);
        p += __shfl_xor(p, 32);
        if (quad == 0) evals[(tile * 32 + e) * 2 + head] = p;

        if (next < NT) {
            stage(b ^ 1);
            __syncthreads();
        }
        b ^= 1;
        tile = next;
    }
}

// ---------------- per-dst softmax + aggregation -> aggb bf16 ----------------
__global__ __launch_bounds__(256) void k_soft_agg(
    const int* __restrict__ rowptr, const int* __restrict__ src_s,
    const float* __restrict__ evals, const bf16_t* __restrict__ s,
    unsigned* __restrict__ aggb)   // [NPAD][64] uints = [NPAD][128] bf16
{
    int lane = threadIdx.x & 63;
    int wid = (blockIdx.x * 256 + threadIdx.x) >> 6;
    int nw = (gridDim.x * 256) >> 6;
    const int h1 = (lane >= 32) ? 1 : 0;
    const int half = lane & 31;
    for (int n = wid; n < N_NODES; n += nw) {
        int r0 = rowptr[n], r1 = rowptr[n + 1];
        unsigned* aout = aggb + (size_t)n * 64 + lane;
        if (r0 == r1) { *aout = 0u; continue; }
        float mm = -1e30f;
        for (int i = r0 + half; i < r1; i += 32) mm = fmaxf(mm, evals[2 * i + h1]);
#pragma unroll
        for (int off = 1; off < 32; off <<= 1) mm = fmaxf(mm, __shfl_xor(mm, off));
        float z = 0.f;
        for (int i = r0 + half; i < r1; i += 32) z += expf(evals[2 * i + h1] - mm);
#pragma unroll
        for (int off = 1; off < 32; off <<= 1) z += __shfl_xor(z, off);
        float rz = 1.f / z;
        float acc0 = 0.f, acc1 = 0.f;
        // batched x16 to keep many gathers in flight
        for (int i = r0; i < r1; i += 16) {
            int cnt = r1 - i;
            unsigned cc[16]; float ww[16];
#pragma unroll
            for (int j = 0; j < 16; j++) {
                if (j < cnt) {
                    cc[j] = *(const unsigned*)(s + (size_t)src_s[i + j] * 384 + 256 + 2 * lane);
                    ww[j] = expf(evals[2 * (i + j) + h1] - mm) * rz;
                } else { cc[j] = 0u; ww[j] = 0.f; }
            }
#pragma unroll
            for (int j = 0; j < 16; j++) {
                acc0 = fmaf(ww[j], bfl(cc[j]), acc0);
                acc1 = fmaf(ww[j], bfh(cc[j]), acc1);
            }
        }
        *aout = (unsigned)f2bf(acc0) | ((unsigned)f2bf(acc1) << 16);
    }
}

// ---------------- node MLP + residual, MFMA: h' = gelu(agg@W1+b1)@W2+b2 + h ----------------
__global__ __launch_bounds__(256) void k_mlp(
    const bf16_t* __restrict__ aggb, const bf16_t* __restrict__ W1T, const float* __restrict__ b1,
    const bf16_t* __restrict__ W2T, const float* __restrict__ b2,
    const float* __restrict__ hin, float* __restrict__ hout, bf16_t* __restrict__ houtb,
    float* __restrict__ out, int col0)
{
    __shared__ __align__(16) bf16_t aggS[32 * 136];
    __shared__ __align__(16) bf16_t hidS[32 * 136];
    const int t = threadIdx.x;
    const int wave = t >> 6, lane = t & 63, l16 = lane & 15, quad = lane >> 4;
    const int n0 = blockIdx.x * 32;
    {   // stage agg tile: 32 rows x 256B (32B per thread)
        int r = t >> 3, sg = t & 7;
        *(s16x8*)(aggS + r * 136 + sg * 16) =
            *(const s16x8*)(aggb + (size_t)(n0 + r) * 128 + sg * 16);
        *(s16x8*)(aggS + r * 136 + sg * 16 + 8) =
            *(const s16x8*)(aggb + (size_t)(n0 + r) * 128 + sg * 16 + 8);
    }
    __syncthreads();
    const int ng = wave & 1, nh = wave >> 1;
    const int node = n0 + ng * 16 + l16;
    {   // GEMM1 + gelu -> hidS
        const bf16_t* brow = aggS + (ng * 16 + l16) * 136 + quad * 8;
        s16x8 B[4];
#pragma unroll
        for (int ks = 0; ks < 4; ks++) B[ks] = *(const s16x8*)(brow + ks * 32);
#pragma unroll
        for (int nt = 0; nt < 4; nt++) {
            int nb = nh * 64 + nt * 16;
            f32x4 acc = {0.f, 0.f, 0.f, 0.f};
#pragma unroll
            for (int ks = 0; ks < 4; ks++) {
                const s16x8 A = *(const s16x8*)(W1T + (size_t)(nb + l16) * 128 + ks * 32 + quad * 8);
                acc = __builtin_amdgcn_mfma_f32_16x16x32_bf16(A, B[ks], acc, 0, 0, 0);
            }
            const float4 bv = *(const float4*)(b1 + nb + quad * 4);
            ushort4 o;
            o.x = f2bf(gelu_f(acc[0] + bv.x));
            o.y = f2bf(gelu_f(acc[1] + bv.y));
            o.z = f2bf(gelu_f(acc[2] + bv.z));
            o.w = f2bf(gelu_f(acc[3] + bv.w));
            *(ushort4*)(hidS + (ng * 16 + l16) * 136 + nb + quad * 4) = o;
        }
    }
    __syncthreads();
    {   // GEMM2 + bias + residual -> hout/houtb/out
        const int jh = wave >> 1;
        const bf16_t* hrow = hidS + (ng * 16 + l16) * 136 + quad * 8;
        s16x8 H[4];
#pragma unroll
        for (int ks = 0; ks < 4; ks++) H[ks] = *(const s16x8*)(hrow + ks * 32);
#pragma unroll
        for (int jt = 0; jt < 2; jt++) {
            int jb = jh * 32 + jt * 16;
            f32x4 acc = {0.f, 0.f, 0.f, 0.f};
#pragma unroll
            for (int ks = 0; ks < 4; ks++) {
                const s16x8 A = *(const s16x8*)(W2T + (size_t)(jb + l16) * 128 + ks * 32 + quad * 8);
                acc = __builtin_amdgcn_mfma_f32_16x16x32_bf16(A, H[ks], acc, 0, 0, 0);
            }
            int j0 = jb + quad * 4;
            const float4 bv = *(const float4*)(b2 + j0);
            const float4 hv = *(const float4*)(hin + (size_t)node * 64 + j0);
            float4 v;
            v.x = acc[0] + bv.x + hv.x;
            v.y = acc[1] + bv.y + hv.y;
            v.z = acc[2] + bv.z + hv.z;
            v.w = acc[3] + bv.w + hv.w;
            *(float4*)(hout + (size_t)node * 64 + j0) = v;
            ushort4 ob;
            ob.x = f2bf(v.x); ob.y = f2bf(v.y); ob.z = f2bf(v.z); ob.w = f2bf(v.w);
            *(ushort4*)(houtb + (size_t)node * 64 + j0) = ob;
            if (node < N_NODES)
                *(float4*)(out + (size_t)node * 704 + col0 + j0) = v;
        }
    }
}

// ---------------- graph max pooling over node_emb cols 0..351 ----------------
__device__ __forceinline__ unsigned fmap(float v) {
    unsigned u = __float_as_uint(v);
    return (u & 0x80000000u) ? ~u : (u | 0x80000000u);
}

__global__ __launch_bounds__(384) void k_colmax(const float* __restrict__ out, unsigned* __restrict__ gmax) {
    int c = threadIdx.x;
    if (c >= 352) return;
    float m = -1e30f;
    for (int n = blockIdx.x; n < N_NODES; n += gridDim.x)
        m = fmaxf(m, out[(size_t)n * 704 + c]);
    atomicMax(gmax + c, fmap(m));
}

__global__ __launch_bounds__(384) void k_bcast(const unsigned* __restrict__ gmax, float* __restrict__ out) {
    int c = threadIdx.x;
    if (c >= 352) return;
    unsigned u = gmax[c];
    u = (u & 0x80000000u) ? (u ^ 0x80000000u) : ~u;
    float v = __uint_as_float(u);
    for (int n = blockIdx.x; n < N_NODES; n += gridDim.x)
        out[(size_t)n * 704 + 352 + c] = v;
}

// ---------------- host launcher ----------------
extern "C" void kernel_launch(void* const* d_in, const int* in_sizes, int n_in,
                              void* d_out, int out_size, void* d_ws, size_t ws_size,
                              hipStream_t stream)
{
    (void)in_sizes; (void)n_in; (void)out_size; (void)ws_size;
    const float* feat     = (const float*)d_in[0];
    const float* att_rc   = (const float*)d_in[1];
    const float* att_rp   = (const float*)d_in[2];
    const float* type_emb = (const float*)d_in[3];
    const float* rid_emb  = (const float*)d_in[4];
    const float* rc_W     = (const float*)d_in[5];
    const float* rc_b     = (const float*)d_in[6];
    const float* rp_W     = (const float*)d_in[7];
    const float* rp_b     = (const float*)d_in[8];
    const float* fe_W1    = (const float*)d_in[9];
    const float* fe_b1    = (const float*)d_in[10];
    const float* fe_W2    = (const float*)d_in[11];
    const float* fe_b2    = (const float*)d_in[12];
    const float* W_ni     = (const float*)d_in[13];
    const float* W_nj     = (const float*)d_in[14];
    const float* W_fij    = (const float*)d_in[15];
    const float* W_node   = (const float*)d_in[16];
    const float* b_node   = (const float*)d_in[17];
    const float* attn     = (const float*)d_in[18];
    const float* mlp_W1   = (const float*)d_in[19];
    const float* mlp_b1   = (const float*)d_in[20];
    const float* mlp_W2   = (const float*)d_in[21];
    const float* mlp_b2   = (const float*)d_in[22];
    const int* src   = (const int*)d_in[23];
    const int* dst   = (const int*)d_in[24];
    const int* etype = (const int*)d_in[25];
    const int* erid  = (const int*)d_in[26];
    float* out = (float*)d_out;

    // Workspace layout (byte cursor, all chunks 16B aligned).
    char* cur = (char*)d_ws;
    auto alloc = [&](size_t bytes) { char* p = cur; cur += (bytes + 15) & ~(size_t)15; return p; };
    float* h_a    = (float*)alloc((size_t)NPAD * 64 * 4);
    float* h_b    = (float*)alloc((size_t)NPAD * 64 * 4);
    bf16_t* hb_a  = (bf16_t*)alloc((size_t)NPAD * 64 * 2);
    bf16_t* hb_b  = (bf16_t*)alloc((size_t)NPAD * 64 * 2);
    bf16_t* s     = (bf16_t*)alloc((size_t)NPAD * 384 * 2);
    float* ev     = (float*)alloc((size_t)N_EDGES * 2 * 4);
    bf16_t* aggb  = (bf16_t*)alloc((size_t)NPAD * 128 * 2);
    int* deg     = (int*)alloc((size_t)N_NODES * 4);
    int* rowptr  = (int*)alloc((size_t)(N_NODES + 1) * 4);
    int* cursor  = (int*)alloc((size_t)N_NODES * 4);
    int* eidx    = (int*)alloc((size_t)N_EDGES * 4);
    int* src_s   = (int*)alloc((size_t)N_EDGES * 4);
    int* dst_s   = (int*)alloc((size_t)N_EDGES * 4);
    int* etype_s = (int*)alloc((size_t)N_EDGES * 4);
    int* erid_s  = (int*)alloc((size_t)N_EDGES * 4);
    float* rc_s  = (float*)alloc((size_t)N_EDGES * 2 * 4);
    float* rp_s  = (float*)alloc((size_t)N_EDGES * 3 * 4);
    bf16_t* WT   = (bf16_t*)alloc((size_t)NLAYER * 128 * 64 * 2);
    bf16_t* W3T  = (bf16_t*)alloc((size_t)NLAYER * 384 * 64 * 2);
    bf16_t* W1T  = (bf16_t*)alloc((size_t)NLAYER * 128 * 128 * 2);
    bf16_t* W2T  = (bf16_t*)alloc((size_t)NLAYER * 64 * 128 * 2);
    int* bsum    = (int*)alloc(64 * 4);
    int* boff    = (int*)alloc(64 * 4);
    unsigned* gmax = (unsigned*)alloc(352 * 4);

    const int NB = (N_NODES + 1023) / 1024;  // 49

    k_zero32<<<(N_NODES + 255) / 256, 256, 0, stream>>>((unsigned*)deg, N_NODES);
    k_zero32<<<2, 256, 0, stream>>>(gmax, 352);
    k_hist<<<N_EDGES / 256, 256, 0, stream>>>(dst, deg);
    k_scan1<<<NB, 1024, 0, stream>>>(deg, rowptr, bsum);
    k_scan2<<<1, 64, 0, stream>>>(bsum, boff, NB);
    k_scan3<<<NB, 1024, 0, stream>>>(rowptr, boff);
    k_copy<<<(N_NODES + 255) / 256, 256, 0, stream>>>(rowptr, cursor);
    k_scatter<<<N_EDGES / 256, 256, 0, stream>>>(dst, cursor, eidx);
    k_sortgather<<<N_EDGES / 256, 256, 0, stream>>>(eidx, src, dst, etype, erid, att_rc, att_rp,
                                                    src_s, dst_s, etype_s, erid_s, rc_s, rp_s);
    k_wprep<<<(NLAYER * 57344 + 255) / 256, 256, 0, stream>>>(
        W_fij, W_ni, W_nj, W_node, mlp_W1, mlp_W2, WT, W3T, W1T, W2T);
    k_fe<<<N_NODES / 4, 256, 0, stream>>>(feat, fe_W1, fe_b1, fe_W2, fe_b2, h_a, hb_a, out);

    float* hc = h_a;  bf16_t* hbc = hb_a;
    float* hn = h_b;  bf16_t* hbn = hb_b;
    for (int l = 0; l < NLAYER; l++) {
        k_node3<<<NPAD / 32, 256, 0, stream>>>(hbc, W3T + (size_t)l * 384 * 64, b_node + l * 128, s);
        k_edge<<<2560, 256, 0, stream>>>(s, WT + l * 128 * 64, attn + l * 128,
                                         type_emb, rid_emb, rc_W, rc_b, rp_W, rp_b,
                                         rc_s, rp_s, etype_s, erid_s, src_s, dst_s, ev);
        k_soft_agg<<<8192, 256, 0, stream>>>(rowptr, src_s, ev, s, (unsigned*)aggb);
        k_mlp<<<NPAD / 32, 256, 0, stream>>>(aggb, W1T + (size_t)l * 128 * 128, mlp_b1 + l * 128,
                                             W2T + (size_t)l * 64 * 128, mlp_b2 + l * 64,
                                             hc, hn, hbn, out, 32 + 64 * (l + 1));
        float* tf = hc; hc = hn; hn = tf;
        bf16_t* tb = hbc; hbc = hbn; hbn = tb;
    }
    k_colmax<<<512, 384, 0, stream>>>(out, gmax);
    k_bcast<<<512, 384, 0, stream>>>(gmax, out);
}